// Round 1
// baseline (1074.741 us; speedup 1.0000x reference)
//
#include <hip/hip_runtime.h>

// ---- problem constants ----
#define NB 64
#define NL 256
#define NH 16
#define ND 64
#define NC 256
#define NK 8
#define NS 30          // SAMPLE_K = N_TOP = 30
#define ICH 16384      // L*D
#define CKN 2048       // C*K
#define MROWS 1024     // B*H
#define NSTEP 256      // ICH / 64

typedef _Float16 h4 __attribute__((ext_vector_type(4)));
typedef _Float16 h8 __attribute__((ext_vector_type(8)));
typedef float f4v __attribute__((ext_vector_type(4)));

// split f32 into hi/lo f16 pair, pre-scaled by 256 (exact pow2) so the lo part
// of the small weights (|w| <= 1/128) stays in f16 normal range.
__device__ __forceinline__ void split4(const float4& x, h4& hi, h4& lo) {
  const float* xp = &x.x;
#pragma unroll
  for (int j = 0; j < 4; ++j) {
    float xs = xp[j] * 256.0f;
    _Float16 hh = (_Float16)xs;
    hi[j] = hh;
    lo[j] = (_Float16)(xs - (float)hh);
  }
}

// ============================================================================
// GEMM: qw/kw[r][n] = sum_i act[r][i] * W[n][i] + bias[n]
//   r = b*16+h (1024 rows), n = c*8+k (2048), i = l*64+d (16384)
//   act[r][i] = activations[b, l, h, d]  (b=r>>4, h=r&15, l=i>>6, d=i&63)
// 128x128 tile, BK=64, 8 waves (2x4 wave grid, 64x32 per wave),
// 3-pass f16-split MFMA 16x16x32, double-buffered 128KB LDS.
// ============================================================================
__global__ __launch_bounds__(512, 2) void gemm_split3(
    const float* __restrict__ qin, const float* __restrict__ kin,
    const float* __restrict__ Wq, const float* __restrict__ bq,
    const float* __restrict__ Wk, const float* __restrict__ bk,
    float* __restrict__ qw, float* __restrict__ kw) {
  // [buf][Ah,Al,Bh,Bl][row][col]  = 2*4*128*64*2B = 128 KiB
  __shared__ __align__(16) _Float16 lds[2][4][128][64];

  const int tile_n = blockIdx.x;  // 0..15
  const int tile_m = blockIdx.y;  // 0..7
  const int z = blockIdx.z;       // 0=q, 1=k
  const float* act = z ? kin : qin;
  const float* W = z ? Wk : Wq;
  const float* bias = z ? bk : bq;
  float* outp = z ? kw : qw;

  const int tid = threadIdx.x;
  const int srow = tid >> 4;          // 0..31
  const int scol = (tid & 15) << 2;   // 0,4,..,60

  // staging base pointers (4 rows per thread: r = q2*32 + srow)
  const float* aB[4];
  const float* bB[4];
#pragma unroll
  for (int q2 = 0; q2 < 4; ++q2) {
    int r = q2 * 32 + srow;
    aB[q2] = act + (size_t)(tile_m * 8 + (r >> 4)) * 262144 + (r & 15) * 64 + scol;
    bB[q2] = W + (size_t)(tile_n * 128 + r) * 16384 + scol;
  }

  const int lane = tid & 63;
  const int wv = tid >> 6;     // wave 0..7
  const int wm = wv >> 2;      // 0..1  (64-row slice)
  const int wn = wv & 3;       // 0..3  (32-col slice)
  const int lr = lane & 15;
  const int lk = lane >> 4;

  f4v acc[4][2];
#pragma unroll
  for (int i = 0; i < 4; ++i)
#pragma unroll
    for (int j = 0; j < 2; ++j) acc[i][j] = (f4v){0.f, 0.f, 0.f, 0.f};

  float4 aS[4], bS[4];

  auto LOADT = [&](int t) {
#pragma unroll
    for (int q2 = 0; q2 < 4; ++q2) {
      aS[q2] = *(const float4*)(aB[q2] + (size_t)t * 1024);
      bS[q2] = *(const float4*)(bB[q2] + (size_t)t * 64);
    }
  };
  auto WRITES = [&](int bufi) {
#pragma unroll
    for (int q2 = 0; q2 < 4; ++q2) {
      int r = q2 * 32 + srow;
      int cs = scol ^ ((r & 7) << 3);  // XOR swizzle (bank-conflict fix)
      h4 hi, lo;
      split4(aS[q2], hi, lo);
      *(h4*)&lds[bufi][0][r][cs] = hi;
      *(h4*)&lds[bufi][1][r][cs] = lo;
      split4(bS[q2], hi, lo);
      *(h4*)&lds[bufi][2][r][cs] = hi;
      *(h4*)&lds[bufi][3][r][cs] = lo;
    }
  };
  auto COMPUTE = [&](int bufi) {
#pragma unroll
    for (int kk = 0; kk < 2; ++kk) {
      const int colb = kk * 32 + lk * 8;
      h8 Ahf[4], Alf[4], Bhf[2], Blf[2];
#pragma unroll
      for (int fr = 0; fr < 4; ++fr) {
        int row = wm * 64 + fr * 16 + lr;
        int col = colb ^ ((row & 7) << 3);
        Ahf[fr] = *(const h8*)&lds[bufi][0][row][col];
        Alf[fr] = *(const h8*)&lds[bufi][1][row][col];
      }
#pragma unroll
      for (int fn = 0; fn < 2; ++fn) {
        int row = wn * 32 + fn * 16 + lr;
        int col = colb ^ ((row & 7) << 3);
        Bhf[fn] = *(const h8*)&lds[bufi][2][row][col];
        Blf[fn] = *(const h8*)&lds[bufi][3][row][col];
      }
#pragma unroll
      for (int fr = 0; fr < 4; ++fr)
#pragma unroll
        for (int fn = 0; fn < 2; ++fn) {
          acc[fr][fn] = __builtin_amdgcn_mfma_f32_16x16x32_f16(Ahf[fr], Bhf[fn], acc[fr][fn], 0, 0, 0);
          acc[fr][fn] = __builtin_amdgcn_mfma_f32_16x16x32_f16(Ahf[fr], Blf[fn], acc[fr][fn], 0, 0, 0);
          acc[fr][fn] = __builtin_amdgcn_mfma_f32_16x16x32_f16(Alf[fr], Bhf[fn], acc[fr][fn], 0, 0, 0);
        }
    }
  };

  LOADT(0);
  WRITES(0);
  __syncthreads();
  int cur = 0;
  for (int t = 0; t < NSTEP; ++t) {
    if (t + 1 < NSTEP) LOADT(t + 1);   // issue next-tile loads early
    COMPUTE(cur);
    if (t + 1 < NSTEP) WRITES(cur ^ 1);  // other buffer: safe concurrently
    __syncthreads();
    cur ^= 1;
  }

  // epilogue: acc * 2^-16 (undo 256*256 scaling) + bias
  float bias2[2];
#pragma unroll
  for (int fn = 0; fn < 2; ++fn)
    bias2[fn] = bias[tile_n * 128 + wn * 32 + fn * 16 + lr];
#pragma unroll
  for (int fr = 0; fr < 4; ++fr)
#pragma unroll
    for (int fn = 0; fn < 2; ++fn) {
      int ocol = tile_n * 128 + wn * 32 + fn * 16 + lr;
#pragma unroll
      for (int j = 0; j < 4; ++j) {
        int orow = tile_m * 128 + wm * 64 + fr * 16 + lk * 4 + j;
        outp[(size_t)orow * CKN + ocol] = acc[fr][fn][j] * (1.0f / 65536.0f) + bias2[fn];
      }
    }
}

// ============================================================================
// Fused tail: per (b,h) block does sampled-QK^T -> M -> top-30 -> scores ->
// causal mask -> softmax -> upd = attn@v -> cumsum(v) with scatter-replace.
// ============================================================================
__global__ __launch_bounds__(256) void attn_tail(
    const float* __restrict__ qw, const float* __restrict__ kw,
    const float* __restrict__ values, const int* __restrict__ isamp,
    float* __restrict__ out) {
  __shared__ __align__(16) float qrow[256][9];   // pad 9: bank spread
  __shared__ __align__(16) float krow[256][9];
  __shared__ __align__(16) float vtile[256][64];
  __shared__ float attnw[256];
  __shared__ float updL[30][64];
  __shared__ float Mv[256];
  __shared__ int idxl[30];
  __shared__ int flagl[256];
  __shared__ float redm[4], reds[4];
  __shared__ int redi[4];
  __shared__ float ctot[4][64];

  const int bh = blockIdx.x;
  const int b = bh >> 4, h = bh & 15;
  const int tid = threadIdx.x;

  // ---- load qw/kw rows + v tile ----
  {
    const float4* qsrc = (const float4*)(qw + (size_t)bh * CKN);
    const float4* ksrc = (const float4*)(kw + (size_t)bh * CKN);
#pragma unroll
    for (int rep = 0; rep < 2; ++rep) {
      int i = rep * 256 + tid;
      int c = i >> 1, p0 = (i & 1) * 4;
      float4 v = qsrc[i];
      qrow[c][p0] = v.x; qrow[c][p0 + 1] = v.y; qrow[c][p0 + 2] = v.z; qrow[c][p0 + 3] = v.w;
      v = ksrc[i];
      krow[c][p0] = v.x; krow[c][p0 + 1] = v.y; krow[c][p0 + 2] = v.z; krow[c][p0 + 3] = v.w;
    }
    const float* vbase = values + (size_t)b * 262144 + h * 64;  // values[b,c,h,d]
#pragma unroll
    for (int rep = 0; rep < 16; ++rep) {
      int i = rep * 256 + tid;
      int c = i >> 4, f4i = i & 15;
      *(float4*)&vtile[c][f4i * 4] = *(const float4*)(vbase + (size_t)c * 1024 + f4i * 4);
    }
    flagl[tid] = 0;
  }
  __syncthreads();

  // ---- M[c] = max_s QKs - sum_s QKs / 256 ----
  {
    float mx = -INFINITY, sm = 0.0f;
    const int c = tid;
#pragma unroll 6
    for (int s = 0; s < NS; ++s) {
      int j = isamp[c * NS + s];
      float dot = 0.0f;
#pragma unroll
      for (int k = 0; k < NK; ++k) dot += qrow[c][k] * krow[j][k];
      mx = fmaxf(mx, dot);
      sm += dot;
    }
    Mv[c] = mx - sm * (1.0f / 256.0f);
  }
  __syncthreads();

  // ---- top-30 (iterative argmax, tie -> lower index, matches lax.top_k) ----
  for (int u = 0; u < NS; ++u) {
    float v = Mv[tid];
    int idx = tid;
#pragma unroll
    for (int off = 32; off > 0; off >>= 1) {
      float ov = __shfl_xor(v, off);
      int oi = __shfl_xor(idx, off);
      if (ov > v || (ov == v && oi < idx)) { v = ov; idx = oi; }
    }
    if ((tid & 63) == 0) { redm[tid >> 6] = v; redi[tid >> 6] = idx; }
    __syncthreads();
    if (tid == 0) {
      float bv = redm[0]; int bi = redi[0];
#pragma unroll
      for (int w2 = 1; w2 < 4; ++w2)
        if (redm[w2] > bv || (redm[w2] == bv && redi[w2] < bi)) { bv = redm[w2]; bi = redi[w2]; }
      idxl[u] = bi;
      flagl[bi] = u + 1;
      Mv[bi] = -INFINITY;
    }
    __syncthreads();
  }

  // ---- per selected query: scores -> mask -> softmax -> upd ----
  const int g = tid >> 6, d = tid & 63;
  for (int u = 0; u < NS; ++u) {
    const int qi = idxl[u];
    float s = 0.0f;
#pragma unroll
    for (int k = 0; k < NK; ++k) s += qrow[qi][k] * krow[tid][k];
    s *= 0.125f;                       // SCALE = 1/sqrt(64)
    if (tid > qi) s = -INFINITY;       // causal mask c > idx[u]
    float m = s;
#pragma unroll
    for (int off = 32; off > 0; off >>= 1) m = fmaxf(m, __shfl_xor(m, off));
    if ((tid & 63) == 0) redm[tid >> 6] = m;
    __syncthreads();
    m = fmaxf(fmaxf(redm[0], redm[1]), fmaxf(redm[2], redm[3]));
    float p = __expf(s - m);           // exp(-inf)=0 for masked
    float tsum = p;
#pragma unroll
    for (int off = 32; off > 0; off >>= 1) tsum += __shfl_xor(tsum, off);
    if ((tid & 63) == 0) reds[tid >> 6] = tsum;
    __syncthreads();
    tsum = ((reds[0] + reds[1]) + reds[2]) + reds[3];
    attnw[tid] = p / tsum;
    __syncthreads();
    // upd[u][d] = sum_c attn[c] * v[c][d]   (4 c-chunks in parallel)
    float accu = 0.0f;
#pragma unroll 8
    for (int i = 0; i < 64; ++i) {
      int cc = g * 64 + i;
      accu += attnw[cc] * vtile[cc][d];
    }
    ctot[g][d] = accu;
    __syncthreads();
    if (tid < 64) updL[u][tid] = ((ctot[0][tid] + ctot[1][tid]) + ctot[2][tid]) + ctot[3][tid];
    __syncthreads();
  }

  // ---- cumsum(v) along l, scatter-replace selected rows, write out ----
  {
    float cs = 0.0f;
#pragma unroll 8
    for (int i = 0; i < 64; ++i) cs += vtile[g * 64 + i][d];
    ctot[g][d] = cs;
    __syncthreads();
    float off0 = 0.0f;
    for (int j = 0; j < g; ++j) off0 += ctot[j][d];
    float run = off0;
    float* obase = out + (size_t)bh * (256 * 64);
    for (int i = 0; i < 64; ++i) {
      int l = g * 64 + i;
      run += vtile[l][d];
      int f = flagl[l];
      obase[(size_t)l * 64 + d] = f ? updL[f - 1][d] : run;
    }
  }
}

extern "C" void kernel_launch(void* const* d_in, const int* in_sizes, int n_in,
                              void* d_out, int out_size, void* d_ws, size_t ws_size,
                              hipStream_t stream) {
  (void)in_sizes; (void)n_in; (void)out_size; (void)ws_size;
  const float* queries = (const float*)d_in[0];
  const float* keys = (const float*)d_in[1];
  const float* values = (const float*)d_in[2];
  const float* Wq_w = (const float*)d_in[3];
  const float* Wq_b = (const float*)d_in[4];
  const float* Wk_w = (const float*)d_in[5];
  const float* Wk_b = (const float*)d_in[6];
  // d_in[7], d_in[8] (Wv_w, Wv_b): dead in reference. d_in[10] attn_mask: unused.
  const int* index_sample = (const int*)d_in[9];
  float* out = (float*)d_out;

  float* qwp = (float*)d_ws;                     // [1024][2048] f32 (8 MB)
  float* kwp = qwp + (size_t)MROWS * CKN;        // [1024][2048] f32 (8 MB)

  dim3 gridG(16, 8, 2);
  gemm_split3<<<gridG, 512, 0, stream>>>(queries, keys, Wq_w, Wq_b, Wk_w, Wk_b, qwp, kwp);
  attn_tail<<<dim3(MROWS), 256, 0, stream>>>(qwp, kwp, values, index_sample, out);
}

// Round 2
// 860.482 us; speedup vs baseline: 1.2490x; 1.2490x over previous
//
#include <hip/hip_runtime.h>

// ---- problem constants ----
#define NB 64
#define NH 16
#define NC 256
#define NK 8
#define NS 30          // SAMPLE_K = N_TOP = 30
#define ICHN 16384     // L*D
#define CKN 2048       // C*K
#define MROWS 1024     // B*H
#define BKF 32         // K f32 elems per step
#define NSTEPS 512     // ICHN / BKF

typedef _Float16 h4 __attribute__((ext_vector_type(4)));
typedef _Float16 h8 __attribute__((ext_vector_type(8)));
typedef float f4v __attribute__((ext_vector_type(4)));

// split f32 into hi/lo f16 pair, pre-scaled by 256 (exact pow2) so the lo part
// of the small weights (|w| <= 1/128) stays in f16 normal range.
__device__ __forceinline__ void split4(const float4& x, h4& hi, h4& lo) {
  const float* xp = &x.x;
#pragma unroll
  for (int j = 0; j < 4; ++j) {
    float xs = xp[j] * 256.0f;
    _Float16 hh = (_Float16)xs;
    hi[j] = hh;
    lo[j] = (_Float16)(xs - (float)hh);
  }
}

// ============================================================================
// GEMM: qw/kw[r][n] = sum_i act[r][i] * W[n][i] + bias[n]
// Tile M128 x N64, BK=32(f32), 256 threads (4 waves, wave-tile 64x32),
// 3-pass f16-split MFMA 16x16x32, double-buffered 48 KiB LDS -> 2 blocks/CU.
// LDS row layout: 64 f16 = [hi chunks 0-3 | lo chunks 4-7], 16B chunks
// XOR-swizzled by (row&7) -> 2-way (free) read conflicts.
// ============================================================================
__global__ __launch_bounds__(256, 3) void gemm_split3(
    const float* __restrict__ qin, const float* __restrict__ kin,
    const float* __restrict__ Wq, const float* __restrict__ bq,
    const float* __restrict__ Wk, const float* __restrict__ bk,
    float* __restrict__ qw, float* __restrict__ kw) {
  __shared__ __align__(16) _Float16 ldsA[2][128][64];  // 32 KiB
  __shared__ __align__(16) _Float16 ldsB[2][64][64];   // 16 KiB

  const int tile_n = blockIdx.x;  // 0..31
  const int tile_m = blockIdx.y;  // 0..7
  const int z = blockIdx.z;       // 0=q, 1=k
  const float* act = z ? kin : qin;
  const float* W = z ? Wk : Wq;
  const float* bias = z ? bk : bq;
  float* outp = z ? kw : qw;

  const int tid = threadIdx.x;

  // staging: A tile = 128x32 f32 = 1024 16B-chunks (4/thread),
  //          B tile =  64x32 f32 =  512 16B-chunks (2/thread)
  int rA[4], jA[4]; const float* aP[4];
  int rB[2], jB[2]; const float* bP[2];
#pragma unroll
  for (int cc = 0; cc < 4; ++cc) {
    int c = tid + cc * 256;
    int r = c >> 3, j = c & 7;
    rA[cc] = r; jA[cc] = j;
    int R = tile_m * 128 + r;                       // global M row
    // act[b,l,h,d]: addr = b*262144 + l*1024 + h*64 + d ; b=R>>4, h=R&15
    aP[cc] = act + (size_t)(R >> 4) * 262144 + (R & 15) * 64 + j * 4;
  }
#pragma unroll
  for (int cc = 0; cc < 2; ++cc) {
    int c = tid + cc * 256;
    int r = c >> 3, j = c & 7;
    rB[cc] = r; jB[cc] = j;
    int n = tile_n * 64 + r;                        // global N row
    bP[cc] = W + (size_t)n * ICHN + j * 4;
  }

  const int lane = tid & 63;
  const int wv = tid >> 6;     // wave 0..3
  const int wm = wv >> 1;      // 0..1  (64-row slice)
  const int wn = wv & 1;       // 0..1  (32-col slice)
  const int lr = lane & 15;
  const int lk = lane >> 4;

  f4v acc[4][2];
#pragma unroll
  for (int i = 0; i < 4; ++i)
#pragma unroll
    for (int j = 0; j < 2; ++j) acc[i][j] = (f4v){0.f, 0.f, 0.f, 0.f};

  float4 aS[4], bS[2];

  auto LOADT = [&](int t) {
    // A k-index i = t*32 + j*4 + e  ->  l = t>>1, d = (t&1)*32 + j*4 + e
    const size_t aoff = (size_t)(t >> 1) * 1024 + (t & 1) * 32;
    const size_t boff = (size_t)t * 32;
#pragma unroll
    for (int cc = 0; cc < 4; ++cc) aS[cc] = *(const float4*)(aP[cc] + aoff);
#pragma unroll
    for (int cc = 0; cc < 2; ++cc) bS[cc] = *(const float4*)(bP[cc] + boff);
  };
  auto WRITES = [&](int bufi) {
    _Float16* bA = &ldsA[bufi][0][0];
    _Float16* bB = &ldsB[bufi][0][0];
#pragma unroll
    for (int cc = 0; cc < 4; ++cc) {
      int r = rA[cc], j = jA[cc];
      int q = j >> 1, hf = j & 1, sw = r & 7;
      h4 hi, lo;
      split4(aS[cc], hi, lo);
      *(h4*)(bA + r * 64 + ((q ^ sw) << 3) + (hf << 2)) = hi;
      *(h4*)(bA + r * 64 + (((q | 4) ^ sw) << 3) + (hf << 2)) = lo;
    }
#pragma unroll
    for (int cc = 0; cc < 2; ++cc) {
      int r = rB[cc], j = jB[cc];
      int q = j >> 1, hf = j & 1, sw = r & 7;
      h4 hi, lo;
      split4(bS[cc], hi, lo);
      *(h4*)(bB + r * 64 + ((q ^ sw) << 3) + (hf << 2)) = hi;
      *(h4*)(bB + r * 64 + (((q | 4) ^ sw) << 3) + (hf << 2)) = lo;
    }
  };
  auto COMPUTE = [&](int bufi) {
    const _Float16* bA = &ldsA[bufi][0][0];
    const _Float16* bB = &ldsB[bufi][0][0];
    h8 Ah[4], Al[4], Bh[2], Bl[2];
#pragma unroll
    for (int fr = 0; fr < 4; ++fr) {
      int row = wm * 64 + fr * 16 + lr;
      int sw = row & 7;
      Ah[fr] = *(const h8*)(bA + row * 64 + ((lk ^ sw) << 3));
      Al[fr] = *(const h8*)(bA + row * 64 + (((lk | 4) ^ sw) << 3));
    }
#pragma unroll
    for (int fn = 0; fn < 2; ++fn) {
      int row = wn * 32 + fn * 16 + lr;
      int sw = row & 7;
      Bh[fn] = *(const h8*)(bB + row * 64 + ((lk ^ sw) << 3));
      Bl[fn] = *(const h8*)(bB + row * 64 + (((lk | 4) ^ sw) << 3));
    }
#pragma unroll
    for (int fr = 0; fr < 4; ++fr)
#pragma unroll
      for (int fn = 0; fn < 2; ++fn) {
        acc[fr][fn] = __builtin_amdgcn_mfma_f32_16x16x32_f16(Ah[fr], Bh[fn], acc[fr][fn], 0, 0, 0);
        acc[fr][fn] = __builtin_amdgcn_mfma_f32_16x16x32_f16(Ah[fr], Bl[fn], acc[fr][fn], 0, 0, 0);
        acc[fr][fn] = __builtin_amdgcn_mfma_f32_16x16x32_f16(Al[fr], Bh[fn], acc[fr][fn], 0, 0, 0);
      }
  };

  LOADT(0);
  WRITES(0);
  __syncthreads();
  int cur = 0;
  for (int t = 0; t < NSTEPS; ++t) {
    if (t + 1 < NSTEPS) LOADT(t + 1);   // issue next-step loads early
    COMPUTE(cur);
    if (t + 1 < NSTEPS) WRITES(cur ^ 1);  // other buffer: safe concurrently
    __syncthreads();
    cur ^= 1;
  }

  // epilogue: acc * 2^-16 (undo 256*256 scaling) + bias
  float bias2[2];
#pragma unroll
  for (int fn = 0; fn < 2; ++fn)
    bias2[fn] = bias[tile_n * 64 + wn * 32 + fn * 16 + lr];
#pragma unroll
  for (int fr = 0; fr < 4; ++fr)
#pragma unroll
    for (int fn = 0; fn < 2; ++fn) {
      int ocol = tile_n * 64 + wn * 32 + fn * 16 + lr;
#pragma unroll
      for (int j = 0; j < 4; ++j) {
        int orow = tile_m * 128 + wm * 64 + fr * 16 + lk * 4 + j;
        outp[(size_t)orow * CKN + ocol] = acc[fr][fn][j] * (1.0f / 65536.0f) + bias2[fn];
      }
    }
}

// ============================================================================
// Fused tail: per (b,h): sampled-QK^T -> M -> top-30 (single wave) ->
// per-wave scores/softmax/upd (wave-local, no block barriers) ->
// cumsum(v) with flagged rows skipped.  ~76 KB LDS -> 2 blocks/CU.
// ============================================================================
__global__ __launch_bounds__(256, 2) void attn_tail(
    const float* __restrict__ qw, const float* __restrict__ kw,
    const float* __restrict__ values, const int* __restrict__ isamp,
    float* __restrict__ out) {
  __shared__ float krow[256][9];                 // padded: 2-way on scores
  __shared__ __align__(16) float vtile[256][64];
  __shared__ float MvC[256];                     // M values; reused as ctot
  __shared__ float qsel[NS][8];
  __shared__ int idxl[NS];
  __shared__ int flagl[256];

  const int bh = blockIdx.x;
  const int b = bh >> 4, h = bh & 15;
  const int tid = threadIdx.x;
  const int w = tid >> 6, lane = tid & 63;

  // ---- phase 0: stage krow + vtile, init flags; q row -> regs ----
  {
    const float4* ksrc = (const float4*)(kw + (size_t)bh * CKN);
#pragma unroll
    for (int rep = 0; rep < 2; ++rep) {
      int i = rep * 256 + tid;
      int c = i >> 1, p0 = (i & 1) * 4;
      float4 v = ksrc[i];
      krow[c][p0] = v.x; krow[c][p0 + 1] = v.y; krow[c][p0 + 2] = v.z; krow[c][p0 + 3] = v.w;
    }
    const float* vbase = values + (size_t)b * 262144 + h * 64;  // values[b,c,h,d]
#pragma unroll
    for (int rep = 0; rep < 16; ++rep) {
      int i = rep * 256 + tid;
      int c = i >> 4, q4 = i & 15;
      *(float4*)&vtile[c][q4 * 4] = *(const float4*)(vbase + (size_t)c * 1024 + q4 * 4);
    }
    flagl[tid] = 0;
  }
  float qq[8];
  {
    const float* qr = qw + (size_t)bh * CKN + tid * 8;
    float4 qa = *(const float4*)qr;
    float4 qb = *(const float4*)(qr + 4);
    qq[0] = qa.x; qq[1] = qa.y; qq[2] = qa.z; qq[3] = qa.w;
    qq[4] = qb.x; qq[5] = qb.y; qq[6] = qb.z; qq[7] = qb.w;
  }
  __syncthreads();

  // ---- phase 1: M[c] = max_s QKs - sum_s QKs / 256 ----
  {
    float mx = -INFINITY, sm = 0.0f;
    const int* ip = isamp + tid * NS;
#pragma unroll 6
    for (int s = 0; s < NS; ++s) {
      int j = ip[s];
      float dot = 0.0f;
#pragma unroll
      for (int k = 0; k < NK; ++k) dot += qq[k] * krow[j][k];
      mx = fmaxf(mx, dot);
      sm += dot;
    }
    MvC[tid] = mx - sm * (1.0f / 256.0f);
  }
  __syncthreads();

  // ---- phase 2: top-30, single wave, shfl argmax (tie -> lower index) ----
  if (tid < 64) {
    float m0 = MvC[tid], m1 = MvC[tid + 64], m2 = MvC[tid + 128], m3 = MvC[tid + 192];
    for (int u = 0; u < NS; ++u) {
      float bv = m0; int bi = tid;
      if (m1 > bv) { bv = m1; bi = tid + 64; }
      if (m2 > bv) { bv = m2; bi = tid + 128; }
      if (m3 > bv) { bv = m3; bi = tid + 192; }
#pragma unroll
      for (int off = 32; off > 0; off >>= 1) {
        float ov = __shfl_xor(bv, off);
        int oi = __shfl_xor(bi, off);
        if (ov > bv || (ov == bv && oi < bi)) { bv = ov; bi = oi; }
      }
      if (tid == 0) { idxl[u] = bi; flagl[bi] = u + 1; }
      if (tid == (bi & 63)) {
        switch (bi >> 6) {
          case 0: m0 = -INFINITY; break;
          case 1: m1 = -INFINITY; break;
          case 2: m2 = -INFINITY; break;
          default: m3 = -INFINITY; break;
        }
      }
    }
  }
  __syncthreads();

  // ---- phase 3: gather selected q rows ----
  if (tid < NS * 8) {
    int u = tid >> 3, k = tid & 7;
    qsel[u][k] = qw[(size_t)bh * CKN + idxl[u] * 8 + k];
  }
  __syncthreads();

  // ---- phase 4: per-wave u: scores -> softmax -> upd -> direct store ----
  float* obase = out + (size_t)bh * 16384;
  for (int ui = w; ui < NS; ui += 4) {
    const int qi = idxl[ui];
    float qv[8];
#pragma unroll
    for (int k = 0; k < 8; ++k) qv[k] = qsel[ui][k];   // LDS broadcast
    float sj[4];
#pragma unroll
    for (int j = 0; j < 4; ++j) {
      int c = j * 64 + lane;
      float s = 0.0f;
#pragma unroll
      for (int k = 0; k < NK; ++k) s += qv[k] * krow[c][k];
      sj[j] = (c > qi) ? -INFINITY : s * 0.125f;       // SCALE=1/8, causal
    }
    float m = fmaxf(fmaxf(sj[0], sj[1]), fmaxf(sj[2], sj[3]));
#pragma unroll
    for (int off = 32; off > 0; off >>= 1) m = fmaxf(m, __shfl_xor(m, off));
    float pj[4], ts = 0.0f;
#pragma unroll
    for (int j = 0; j < 4; ++j) { pj[j] = __expf(sj[j] - m); ts += pj[j]; }
#pragma unroll
    for (int off = 32; off > 0; off >>= 1) ts += __shfl_xor(ts, off);
    float rinv = 1.0f / ts;
#pragma unroll
    for (int j = 0; j < 4; ++j) pj[j] *= rinv;
    // upd[d=lane] = sum_c attn[c] * v[c][d]; attn broadcast via readlane
    float accu = 0.0f;
#pragma unroll
    for (int j = 0; j < 4; ++j) {
#pragma unroll
      for (int i = 0; i < 64; ++i) {
        float a = __uint_as_float(__builtin_amdgcn_readlane(__float_as_uint(pj[j]), i));
        accu += a * vtile[j * 64 + i][lane];
      }
    }
    obase[(size_t)qi * 64 + lane] = accu;
  }
  __syncthreads();

  // ---- phase 5: cumsum(v) along l, skip flagged rows ----
  {
    float cs = 0.0f;
#pragma unroll 8
    for (int i = 0; i < 64; ++i) cs += vtile[w * 64 + i][lane];
    MvC[w * 64 + lane] = cs;   // Mv dead after phase 2 -> reuse as ctot
    __syncthreads();
    float run = 0.0f;
    for (int j2 = 0; j2 < w; ++j2) run += MvC[j2 * 64 + lane];
    for (int i = 0; i < 64; ++i) {
      int l = w * 64 + i;
      run += vtile[l][lane];
      if (!flagl[l]) obase[(size_t)l * 64 + lane] = run;
    }
  }
}

extern "C" void kernel_launch(void* const* d_in, const int* in_sizes, int n_in,
                              void* d_out, int out_size, void* d_ws, size_t ws_size,
                              hipStream_t stream) {
  (void)in_sizes; (void)n_in; (void)out_size; (void)ws_size;
  const float* queries = (const float*)d_in[0];
  const float* keys = (const float*)d_in[1];
  const float* values = (const float*)d_in[2];
  const float* Wq_w = (const float*)d_in[3];
  const float* Wq_b = (const float*)d_in[4];
  const float* Wk_w = (const float*)d_in[5];
  const float* Wk_b = (const float*)d_in[6];
  // d_in[7], d_in[8] (Wv_w, Wv_b): dead in reference. d_in[10] attn_mask: unused.
  const int* index_sample = (const int*)d_in[9];
  float* out = (float*)d_out;

  float* qwp = (float*)d_ws;                     // [1024][2048] f32 (8 MB)
  float* kwp = qwp + (size_t)MROWS * CKN;        // [1024][2048] f32 (8 MB)

  dim3 gridG(32, 8, 2);
  gemm_split3<<<gridG, 256, 0, stream>>>(queries, keys, Wq_w, Wq_b, Wk_w, Wk_b, qwp, kwp);
  attn_tail<<<dim3(MROWS), 256, 0, stream>>>(qwp, kwp, values, index_sample, out);
}

// Round 3
// 819.810 us; speedup vs baseline: 1.3110x; 1.0496x over previous
//
#include <hip/hip_runtime.h>

// ---- problem constants ----
#define NC 256
#define NK 8
#define NS 30          // SAMPLE_K = N_TOP = 30
#define ICHN 16384     // L*D
#define CKN 2048       // C*K
#define MROWS 1024     // B*H
#define GSTEPS 256     // K-steps per block: 8192 f32 / 32
#define PLANE ((size_t)MROWS * CKN)   // one partial matrix, f32 elems
#define SCLQ (1.0f / 65536.0f)        // undo 256*256 split pre-scale

typedef _Float16 h4 __attribute__((ext_vector_type(4)));
typedef _Float16 h8 __attribute__((ext_vector_type(8)));
typedef float f4v __attribute__((ext_vector_type(4)));

// split f32 into hi/lo f16 pair, pre-scaled by 256 (exact pow2) so the lo part
// of the small weights (|w| <= 1/128) stays in f16 normal range. (validated r1/r2)
__device__ __forceinline__ void split4(const float4& x, h4& hi, h4& lo) {
  const float* xp = &x.x;
#pragma unroll
  for (int j = 0; j < 4; ++j) {
    float xs = xp[j] * 256.0f;
    _Float16 hh = (_Float16)xs;
    hi[j] = hh;
    lo[j] = (_Float16)(xs - (float)hh);
  }
}

// ============================================================================
// GEMM (K-split): P[z][ks][r][n] = sum_{i in ks-half} act[r][i] * W[n][i]
//   r = b*16+h (1024), n = c*8+k (2048), i = l*64+d (16384)
// Tile M128 x N128, BK=32 f32, 256 threads (4 waves, wave-tile 64x64),
// 3-pass f16-split MFMA 16x16x32, double-buffered 64 KiB LDS -> 2 blocks/CU.
// LDS row = 8 x 16B chunks: k-group q hi at chunk (2q)^(r&7), lo at (2q+1)^(r&7)
// -> both b128 writes and b128 reads are 2 lanes/chunk-slot = conflict-free.
// Scale (2^-16) and bias are applied in attn_tail during the partial reduce.
// ============================================================================
__global__ __launch_bounds__(256, 2) void gemm_split3(
    const float* __restrict__ qin, const float* __restrict__ kin,
    const float* __restrict__ Wq, const float* __restrict__ Wk,
    float* __restrict__ P) {
  __shared__ __align__(16) _Float16 ldsA[2][128][64];  // 32 KiB
  __shared__ __align__(16) _Float16 ldsB[2][128][64];  // 32 KiB

  const int tile_n = blockIdx.x;  // 0..15
  const int tile_m = blockIdx.y;  // 0..7
  const int z2 = blockIdx.z;      // 0..3
  const int zq = z2 >> 1;         // 0=q, 1=k
  const int ks = z2 & 1;          // K-split half
  const float* act = zq ? kin : qin;
  const float* W = zq ? Wk : Wq;
  float* outp = P + (size_t)z2 * PLANE;

  const int tid = threadIdx.x;
  // staging: thread owns group (r, q) and (r+64, q): 8 consecutive f32 each
  const int rA = tid >> 2;        // 0..63
  const int qA = tid & 3;         // k-group 0..3 (8 f32 each)

  const float* aP[2];
  const float* bP[2];
#pragma unroll
  for (int c = 0; c < 2; ++c) {
    int R = tile_m * 128 + rA + 64 * c;   // global M row: b=R>>4, h=R&15
    aP[c] = act + (size_t)(R >> 4) * 262144 + (R & 15) * 64 + ks * 131072 + qA * 8;
    int n = tile_n * 128 + rA + 64 * c;   // global N row
    bP[c] = W + (size_t)n * ICHN + ks * 8192 + qA * 8;
  }
  // LDS write offsets (f16 elems); row+64 adds 4096, swizzle unchanged (64%8==0)
  const int swW = rA & 7;
  const int offH = rA * 64 + (((2 * qA) ^ swW) << 3);
  const int offL = rA * 64 + (((2 * qA + 1) ^ swW) << 3);

  const int lane = tid & 63;
  const int wv = tid >> 6;     // wave 0..3
  const int wm = wv >> 1;      // 0..1  (64-row slice)
  const int wn = wv & 1;       // 0..1  (64-col slice)
  const int lr = lane & 15;
  const int lk = lane >> 4;    // k-group 0..3
  // frag read offsets: row = wm*64+fr*16+lr -> row&7 == lr&7 (lane-const)
  const int swR = lr & 7;
  const int aOffH = (wm * 64 + lr) * 64 + (((2 * lk) ^ swR) << 3);
  const int aOffL = (wm * 64 + lr) * 64 + (((2 * lk + 1) ^ swR) << 3);
  const int bOffH = (wn * 64 + lr) * 64 + (((2 * lk) ^ swR) << 3);
  const int bOffL = (wn * 64 + lr) * 64 + (((2 * lk + 1) ^ swR) << 3);

  f4v acc[4][4];
#pragma unroll
  for (int i = 0; i < 4; ++i)
#pragma unroll
    for (int j = 0; j < 4; ++j) acc[i][j] = (f4v){0.f, 0.f, 0.f, 0.f};

  float4 aSa[2], aSb[2], bSa[2], bSb[2];

  auto LOADT = [&](int t) {
    const size_t aoff = (size_t)(t >> 1) * 1024 + (t & 1) * 32;  // l=t>>1, d+=(t&1)*32
    const size_t boff = (size_t)t * 32;
#pragma unroll
    for (int c = 0; c < 2; ++c) {
      aSa[c] = *(const float4*)(aP[c] + aoff);
      aSb[c] = *(const float4*)(aP[c] + aoff + 4);
      bSa[c] = *(const float4*)(bP[c] + boff);
      bSb[c] = *(const float4*)(bP[c] + boff + 4);
    }
  };
  auto WRITES = [&](int bufi) {
    _Float16* bA = &ldsA[bufi][0][0];
    _Float16* bB = &ldsB[bufi][0][0];
#pragma unroll
    for (int c = 0; c < 2; ++c) {
      h4 h0, l0, h1, l1;
      split4(aSa[c], h0, l0);
      split4(aSb[c], h1, l1);
      *(h8*)(bA + offH + c * 4096) =
          (h8){h0[0], h0[1], h0[2], h0[3], h1[0], h1[1], h1[2], h1[3]};
      *(h8*)(bA + offL + c * 4096) =
          (h8){l0[0], l0[1], l0[2], l0[3], l1[0], l1[1], l1[2], l1[3]};
      split4(bSa[c], h0, l0);
      split4(bSb[c], h1, l1);
      *(h8*)(bB + offH + c * 4096) =
          (h8){h0[0], h0[1], h0[2], h0[3], h1[0], h1[1], h1[2], h1[3]};
      *(h8*)(bB + offL + c * 4096) =
          (h8){l0[0], l0[1], l0[2], l0[3], l1[0], l1[1], l1[2], l1[3]};
    }
  };
  auto COMPUTE = [&](int bufi) {
    const _Float16* bA = &ldsA[bufi][0][0];
    const _Float16* bB = &ldsB[bufi][0][0];
    h8 Ah[4], Al[4], Bh[4], Bl[4];
#pragma unroll
    for (int fr = 0; fr < 4; ++fr) {
      Ah[fr] = *(const h8*)(bA + aOffH + fr * 1024);
      Al[fr] = *(const h8*)(bA + aOffL + fr * 1024);
    }
#pragma unroll
    for (int fn = 0; fn < 4; ++fn) {
      Bh[fn] = *(const h8*)(bB + bOffH + fn * 1024);
      Bl[fn] = *(const h8*)(bB + bOffL + fn * 1024);
    }
    __builtin_amdgcn_s_setprio(1);
#pragma unroll
    for (int fr = 0; fr < 4; ++fr)
#pragma unroll
      for (int fn = 0; fn < 4; ++fn) {
        acc[fr][fn] = __builtin_amdgcn_mfma_f32_16x16x32_f16(Ah[fr], Bh[fn], acc[fr][fn], 0, 0, 0);
        acc[fr][fn] = __builtin_amdgcn_mfma_f32_16x16x32_f16(Ah[fr], Bl[fn], acc[fr][fn], 0, 0, 0);
        acc[fr][fn] = __builtin_amdgcn_mfma_f32_16x16x32_f16(Al[fr], Bh[fn], acc[fr][fn], 0, 0, 0);
      }
    __builtin_amdgcn_s_setprio(0);
  };

  LOADT(0);
  WRITES(0);
  __syncthreads();
  int cur = 0;
  for (int t = 0; t < GSTEPS; ++t) {
    if (t + 1 < GSTEPS) LOADT(t + 1);     // issue next-step loads early
    COMPUTE(cur);
    if (t + 1 < GSTEPS) WRITES(cur ^ 1);  // other buffer: safe concurrently
    __syncthreads();
    cur ^= 1;
  }

  // epilogue: raw partial accumulators (scale+bias applied in attn_tail)
#pragma unroll
  for (int fr = 0; fr < 4; ++fr)
#pragma unroll
    for (int fn = 0; fn < 4; ++fn) {
      int ocol = tile_n * 128 + wn * 64 + fn * 16 + lr;
#pragma unroll
      for (int j = 0; j < 4; ++j) {
        int orow = tile_m * 128 + wm * 64 + fr * 16 + lk * 4 + j;
        outp[(size_t)orow * CKN + ocol] = acc[fr][fn][j];
      }
    }
}

// ============================================================================
// Fused tail: per (b,h): reduce K-split partials (+scale+bias) -> sampled-QK^T
// -> M -> top-30 (single wave) -> per-wave scores/softmax/upd ->
// cumsum(v) with flagged rows skipped.  ~76 KB LDS -> 2 blocks/CU.
// ============================================================================
__global__ __launch_bounds__(256, 2) void attn_tail(
    const float* __restrict__ P, const float* __restrict__ bq,
    const float* __restrict__ bk, const float* __restrict__ values,
    const int* __restrict__ isamp, float* __restrict__ out) {
  __shared__ float krow[256][9];                 // padded: 2-way on scores
  __shared__ __align__(16) float vtile[256][64];
  __shared__ float MvC[256];                     // M values; reused as ctot
  __shared__ float qsel[NS][8];
  __shared__ int idxl[NS];
  __shared__ int flagl[256];

  const float* pq0 = P;
  const float* pq1 = P + PLANE;
  const float* pk0 = P + 2 * PLANE;
  const float* pk1 = P + 3 * PLANE;

  const int bh = blockIdx.x;
  const int b = bh >> 4, h = bh & 15;
  const int tid = threadIdx.x;
  const int w = tid >> 6, lane = tid & 63;

  // ---- phase 0: stage krow (reduced+biased) + vtile, init flags; q row -> regs
  {
#pragma unroll
    for (int rep = 0; rep < 2; ++rep) {
      int i = rep * 256 + tid;                    // float4 index within row
      int c = i >> 1, p0 = (i & 1) * 4;
      float4 v0 = ((const float4*)(pk0 + (size_t)bh * CKN))[i];
      float4 v1 = ((const float4*)(pk1 + (size_t)bh * CKN))[i];
      float4 bb = ((const float4*)bk)[i];
      krow[c][p0]     = (v0.x + v1.x) * SCLQ + bb.x;
      krow[c][p0 + 1] = (v0.y + v1.y) * SCLQ + bb.y;
      krow[c][p0 + 2] = (v0.z + v1.z) * SCLQ + bb.z;
      krow[c][p0 + 3] = (v0.w + v1.w) * SCLQ + bb.w;
    }
    const float* vbase = values + (size_t)b * 262144 + h * 64;  // values[b,c,h,d]
#pragma unroll
    for (int rep = 0; rep < 16; ++rep) {
      int i = rep * 256 + tid;
      int c = i >> 4, q4 = i & 15;
      *(float4*)&vtile[c][q4 * 4] = *(const float4*)(vbase + (size_t)c * 1024 + q4 * 4);
    }
    flagl[tid] = 0;
  }
  float qq[8];
  {
    const size_t i0 = (size_t)bh * CKN + tid * 8;
    float4 a0 = *(const float4*)(pq0 + i0), a1 = *(const float4*)(pq0 + i0 + 4);
    float4 c0 = *(const float4*)(pq1 + i0), c1 = *(const float4*)(pq1 + i0 + 4);
    float4 b0 = *(const float4*)(bq + tid * 8), b1 = *(const float4*)(bq + tid * 8 + 4);
    qq[0] = (a0.x + c0.x) * SCLQ + b0.x; qq[1] = (a0.y + c0.y) * SCLQ + b0.y;
    qq[2] = (a0.z + c0.z) * SCLQ + b0.z; qq[3] = (a0.w + c0.w) * SCLQ + b0.w;
    qq[4] = (a1.x + c1.x) * SCLQ + b1.x; qq[5] = (a1.y + c1.y) * SCLQ + b1.y;
    qq[6] = (a1.z + c1.z) * SCLQ + b1.z; qq[7] = (a1.w + c1.w) * SCLQ + b1.w;
  }
  __syncthreads();

  // ---- phase 1: M[c] = max_s QKs - sum_s QKs / 256 ----
  {
    float mx = -INFINITY, sm = 0.0f;
    const int* ip = isamp + tid * NS;
#pragma unroll 6
    for (int s = 0; s < NS; ++s) {
      int j = ip[s];
      float dot = 0.0f;
#pragma unroll
      for (int k = 0; k < NK; ++k) dot += qq[k] * krow[j][k];
      mx = fmaxf(mx, dot);
      sm += dot;
    }
    MvC[tid] = mx - sm * (1.0f / 256.0f);
  }
  __syncthreads();

  // ---- phase 2: top-30, single wave, shfl argmax (tie -> lower index) ----
  if (tid < 64) {
    float m0 = MvC[tid], m1 = MvC[tid + 64], m2 = MvC[tid + 128], m3 = MvC[tid + 192];
    for (int u = 0; u < NS; ++u) {
      float bv = m0; int bi = tid;
      if (m1 > bv) { bv = m1; bi = tid + 64; }
      if (m2 > bv) { bv = m2; bi = tid + 128; }
      if (m3 > bv) { bv = m3; bi = tid + 192; }
#pragma unroll
      for (int off = 32; off > 0; off >>= 1) {
        float ov = __shfl_xor(bv, off);
        int oi = __shfl_xor(bi, off);
        if (ov > bv || (ov == bv && oi < bi)) { bv = ov; bi = oi; }
      }
      if (tid == 0) { idxl[u] = bi; flagl[bi] = u + 1; }
      if (tid == (bi & 63)) {
        switch (bi >> 6) {
          case 0: m0 = -INFINITY; break;
          case 1: m1 = -INFINITY; break;
          case 2: m2 = -INFINITY; break;
          default: m3 = -INFINITY; break;
        }
      }
    }
  }
  __syncthreads();

  // ---- phase 3: gather selected q rows (reduced+biased) ----
  if (tid < NS * 8) {
    int u = tid >> 3, k = tid & 7;
    size_t off = (size_t)bh * CKN + idxl[u] * 8 + k;
    qsel[u][k] = (pq0[off] + pq1[off]) * SCLQ + bq[idxl[u] * 8 + k];
  }
  __syncthreads();

  // ---- phase 4: per-wave u: scores -> softmax -> upd -> direct store ----
  float* obase = out + (size_t)bh * 16384;
  for (int ui = w; ui < NS; ui += 4) {
    const int qi = idxl[ui];
    float qv[8];
#pragma unroll
    for (int k = 0; k < 8; ++k) qv[k] = qsel[ui][k];   // LDS broadcast
    float sj[4];
#pragma unroll
    for (int j = 0; j < 4; ++j) {
      int c = j * 64 + lane;
      float s = 0.0f;
#pragma unroll
      for (int k = 0; k < NK; ++k) s += qv[k] * krow[c][k];
      sj[j] = (c > qi) ? -INFINITY : s * 0.125f;       // SCALE=1/8, causal
    }
    float m = fmaxf(fmaxf(sj[0], sj[1]), fmaxf(sj[2], sj[3]));
#pragma unroll
    for (int off = 32; off > 0; off >>= 1) m = fmaxf(m, __shfl_xor(m, off));
    float pj[4], ts = 0.0f;
#pragma unroll
    for (int j = 0; j < 4; ++j) { pj[j] = __expf(sj[j] - m); ts += pj[j]; }
#pragma unroll
    for (int off = 32; off > 0; off >>= 1) ts += __shfl_xor(ts, off);
    float rinv = 1.0f / ts;
#pragma unroll
    for (int j = 0; j < 4; ++j) pj[j] *= rinv;
    // upd[d=lane] = sum_c attn[c] * v[c][d]; attn broadcast via readlane
    float accu = 0.0f;
#pragma unroll
    for (int j = 0; j < 4; ++j) {
#pragma unroll
      for (int i = 0; i < 64; ++i) {
        float a = __uint_as_float(__builtin_amdgcn_readlane(__float_as_uint(pj[j]), i));
        accu += a * vtile[j * 64 + i][lane];
      }
    }
    obase[(size_t)qi * 64 + lane] = accu;
  }
  __syncthreads();

  // ---- phase 5: cumsum(v) along l, skip flagged rows ----
  {
    float cs = 0.0f;
#pragma unroll 8
    for (int i = 0; i < 64; ++i) cs += vtile[w * 64 + i][lane];
    MvC[w * 64 + lane] = cs;   // MvC dead after phase 2 -> reuse as chunk totals
    __syncthreads();
    float run = 0.0f;
    for (int j2 = 0; j2 < w; ++j2) run += MvC[j2 * 64 + lane];
    for (int i = 0; i < 64; ++i) {
      int l = w * 64 + i;
      run += vtile[l][lane];
      if (!flagl[l]) obase[(size_t)l * 64 + lane] = run;
    }
  }
}

extern "C" void kernel_launch(void* const* d_in, const int* in_sizes, int n_in,
                              void* d_out, int out_size, void* d_ws, size_t ws_size,
                              hipStream_t stream) {
  (void)in_sizes; (void)n_in; (void)out_size; (void)ws_size;
  const float* queries = (const float*)d_in[0];
  const float* keys = (const float*)d_in[1];
  const float* values = (const float*)d_in[2];
  const float* Wq_w = (const float*)d_in[3];
  const float* Wq_b = (const float*)d_in[4];
  const float* Wk_w = (const float*)d_in[5];
  const float* Wk_b = (const float*)d_in[6];
  // d_in[7], d_in[8] (Wv_w, Wv_b): dead in reference. d_in[10] attn_mask: unused.
  const int* index_sample = (const int*)d_in[9];
  float* out = (float*)d_out;

  float* P = (float*)d_ws;   // 4 partial planes [z][ks][1024][2048] f32 = 33.5 MB

  dim3 gridG(16, 8, 4);
  gemm_split3<<<gridG, 256, 0, stream>>>(queries, keys, Wq_w, Wk_w, P);
  attn_tail<<<dim3(MROWS), 256, 0, stream>>>(P, Wq_b, Wk_b, values, index_sample, out);
}

// Round 4
// 454.886 us; speedup vs baseline: 2.3627x; 1.8022x over previous
//
#include <hip/hip_runtime.h>

// ---- problem constants ----
#define NC 256
#define NK 8
#define NS 30          // SAMPLE_K = N_TOP = 30
#define ICHN 16384     // L*D
#define CKN 2048       // C*K
#define MROWS 1024     // B*H
#define PLANE ((size_t)MROWS * CKN)   // one partial matrix, f32 elems
#define SCLQ (1.0f / 65536.0f)        // undo 256*256 split pre-scale

typedef _Float16 h4 __attribute__((ext_vector_type(4)));
typedef _Float16 h8 __attribute__((ext_vector_type(8)));
typedef float f4v __attribute__((ext_vector_type(4)));

// split f32 into hi/lo f16 pair, pre-scaled by 256 (exact pow2) so the lo part
// of the small weights (|w| <= 1/128) stays in f16 normal range. (validated r1-r3)
__device__ __forceinline__ void split4(const float4& x, h4& hi, h4& lo) {
  const float* xp = &x.x;
#pragma unroll
  for (int j = 0; j < 4; ++j) {
    float xs = xp[j] * 256.0f;
    _Float16 hh = (_Float16)xs;
    hi[j] = hh;
    lo[j] = (_Float16)(xs - (float)hh);
  }
}

// ============================================================================
// GEMM (K-split x KS): P[z*KS+ks][r][n] = sum_{i in ks-slice} act[r][i]*W[n][i]
// Tile M256 x N256, BK=32 f32 (64 f16), 512 threads = 8 waves (2Mx4N),
// wave-tile 128x64, 3-pass f16-split MFMA 16x16x32, double-buffered 128 KiB
// LDS, 1 block/CU. Per block-step: matrix 3725 cyc > LDS 3070 cyc.
// LDS row = 8 x 16B chunks: group q hi at chunk (2q)^(r&7), lo at (2q+1)^(r&7)
// (read+write conflict behavior identical to validated r3 layout).
// Scale (2^-16) and bias are applied in attn_tail during the partial reduce.
// ============================================================================
__global__ __launch_bounds__(512, 2) void gemm_split3(
    const float* __restrict__ qin, const float* __restrict__ kin,
    const float* __restrict__ Wq, const float* __restrict__ Wk,
    float* __restrict__ P, int KS, int KL, int nsteps) {
  __shared__ __align__(16) _Float16 ldsA[2][256][64];  // 64 KiB
  __shared__ __align__(16) _Float16 ldsB[2][256][64];  // 64 KiB

  const int tm = blockIdx.x & 3;   // 4 M-tiles
  const int tn = blockIdx.x >> 2;  // 8 N-tiles
  const int ksi = blockIdx.y;      // K-split slice
  const int z = blockIdx.z;        // 0=q, 1=k
  const float* act = z ? kin : qin;
  const float* W = z ? Wk : Wq;
  float* outp = P + (size_t)(z * KS + ksi) * PLANE;

  const int tid = threadIdx.x;
  // staging: thread owns row r = tid>>1 (of 256), f32 half g = tid&1 (16 f32)
  const int r = tid >> 1;
  const int g = tid & 1;
  const int R = tm * 256 + r;                  // global M row: b=R>>4, h=R&15
  const float* aP = act + (size_t)(R >> 4) * 262144 + (R & 15) * 64 +
                    (size_t)ksi * KL * 16 + g * 16;
  const int n = tn * 256 + r;                  // global N row
  const float* bP = W + (size_t)n * 16384 + (size_t)ksi * KL + g * 16;

  // LDS write offsets: groups q = 2g, 2g+1 -> hi chunk 2q, lo chunk 2q+1
  const int swW = r & 7;
  const int oh0 = r * 64 + (((4 * g + 0) ^ swW) << 3);
  const int ol0 = r * 64 + (((4 * g + 1) ^ swW) << 3);
  const int oh1 = r * 64 + (((4 * g + 2) ^ swW) << 3);
  const int ol1 = r * 64 + (((4 * g + 3) ^ swW) << 3);

  const int lane = tid & 63;
  const int wv = tid >> 6;     // wave 0..7
  const int wm = wv >> 2;      // 0..1  (128-row slice)
  const int wn = wv & 3;       // 0..3  (64-col slice)
  const int lr = lane & 15;
  const int lk = lane >> 4;    // k-group 0..3
  const int swR = lr & 7;
  const int aOffH = (wm * 128 + lr) * 64 + (((2 * lk) ^ swR) << 3);
  const int aOffL = (wm * 128 + lr) * 64 + (((2 * lk + 1) ^ swR) << 3);
  const int bOffH = (wn * 64 + lr) * 64 + (((2 * lk) ^ swR) << 3);
  const int bOffL = (wn * 64 + lr) * 64 + (((2 * lk + 1) ^ swR) << 3);

  f4v acc[8][4];
#pragma unroll
  for (int i = 0; i < 8; ++i)
#pragma unroll
    for (int j = 0; j < 4; ++j) acc[i][j] = (f4v){0.f, 0.f, 0.f, 0.f};

  float4 aS[4], bS[4];

  auto LOADT = [&](int s) {
    const size_t aoff = (size_t)(s >> 1) * 1024 + (s & 1) * 32;  // l=s>>1
    const size_t boff = (size_t)s * 32;
#pragma unroll
    for (int c = 0; c < 4; ++c) {
      aS[c] = *(const float4*)(aP + aoff + c * 4);
      bS[c] = *(const float4*)(bP + boff + c * 4);
    }
  };
  auto WRITES = [&](int bufi) {
    _Float16* bA = &ldsA[bufi][0][0];
    _Float16* bB = &ldsB[bufi][0][0];
    h4 h0, l0, h1, l1;
    split4(aS[0], h0, l0);
    split4(aS[1], h1, l1);
    *(h8*)(bA + oh0) = (h8){h0[0], h0[1], h0[2], h0[3], h1[0], h1[1], h1[2], h1[3]};
    *(h8*)(bA + ol0) = (h8){l0[0], l0[1], l0[2], l0[3], l1[0], l1[1], l1[2], l1[3]};
    split4(aS[2], h0, l0);
    split4(aS[3], h1, l1);
    *(h8*)(bA + oh1) = (h8){h0[0], h0[1], h0[2], h0[3], h1[0], h1[1], h1[2], h1[3]};
    *(h8*)(bA + ol1) = (h8){l0[0], l0[1], l0[2], l0[3], l1[0], l1[1], l1[2], l1[3]};
    split4(bS[0], h0, l0);
    split4(bS[1], h1, l1);
    *(h8*)(bB + oh0) = (h8){h0[0], h0[1], h0[2], h0[3], h1[0], h1[1], h1[2], h1[3]};
    *(h8*)(bB + ol0) = (h8){l0[0], l0[1], l0[2], l0[3], l1[0], l1[1], l1[2], l1[3]};
    split4(bS[2], h0, l0);
    split4(bS[3], h1, l1);
    *(h8*)(bB + oh1) = (h8){h0[0], h0[1], h0[2], h0[3], h1[0], h1[1], h1[2], h1[3]};
    *(h8*)(bB + ol1) = (h8){l0[0], l0[1], l0[2], l0[3], l1[0], l1[1], l1[2], l1[3]};
  };
  auto COMPUTE = [&](int bufi) {
    const _Float16* bA = &ldsA[bufi][0][0];
    const _Float16* bB = &ldsB[bufi][0][0];
    h8 Bh[4], Bl[4];
#pragma unroll
    for (int fn = 0; fn < 4; ++fn) {
      Bh[fn] = *(const h8*)(bB + bOffH + fn * 1024);
      Bl[fn] = *(const h8*)(bB + bOffL + fn * 1024);
    }
#pragma unroll
    for (int half = 0; half < 2; ++half) {
      h8 Ah[4], Al[4];
#pragma unroll
      for (int fr = 0; fr < 4; ++fr) {
        Ah[fr] = *(const h8*)(bA + aOffH + (half * 4 + fr) * 1024);
        Al[fr] = *(const h8*)(bA + aOffL + (half * 4 + fr) * 1024);
      }
      __builtin_amdgcn_s_setprio(1);
#pragma unroll
      for (int fr = 0; fr < 4; ++fr)
#pragma unroll
        for (int fn = 0; fn < 4; ++fn) {
          f4v a = acc[half * 4 + fr][fn];
          a = __builtin_amdgcn_mfma_f32_16x16x32_f16(Ah[fr], Bh[fn], a, 0, 0, 0);
          a = __builtin_amdgcn_mfma_f32_16x16x32_f16(Ah[fr], Bl[fn], a, 0, 0, 0);
          a = __builtin_amdgcn_mfma_f32_16x16x32_f16(Al[fr], Bh[fn], a, 0, 0, 0);
          acc[half * 4 + fr][fn] = a;
        }
      __builtin_amdgcn_s_setprio(0);
    }
  };

  LOADT(0);
  WRITES(0);
  __syncthreads();
  int cur = 0;
  for (int s = 0; s < nsteps; ++s) {
    if (s + 1 < nsteps) LOADT(s + 1);     // issue next-step loads early
    COMPUTE(cur);
    if (s + 1 < nsteps) WRITES(cur ^ 1);  // other buffer: safe concurrently
    __syncthreads();
    cur ^= 1;
  }

  // epilogue: raw partial accumulators (scale+bias applied in attn_tail)
#pragma unroll
  for (int fr = 0; fr < 8; ++fr)
#pragma unroll
    for (int fn = 0; fn < 4; ++fn) {
      int ocol = tn * 256 + wn * 64 + fn * 16 + lr;
#pragma unroll
      for (int j = 0; j < 4; ++j) {
        int orow = tm * 256 + wm * 128 + fr * 16 + lk * 4 + j;
        outp[(size_t)orow * CKN + ocol] = acc[fr][fn][j];
      }
    }
}

// ============================================================================
// Fused tail per (b,h): reduce K-split partials (+scale+bias) -> sampled-QK^T
// -> M -> top-30 (single wave) -> per-wave scores/softmax -> PV via MFMA ->
// cumsum(v as f16) with flagged rows skipped.  ~60 KB LDS -> 2 blocks/CU.
// kT transposed [k][c]: conflict-free stride-1 score reads.
// vT/Pm f16 [row][256] with 16B-chunk XOR swizzle (cidx ^ (row&7)): b128 frag
// reads spread 8 bank-quads (validated pattern from GEMM).
// ============================================================================
__global__ __launch_bounds__(256, 2) void attn_tail(
    const float* __restrict__ P, const float* __restrict__ bq,
    const float* __restrict__ bk, const float* __restrict__ values,
    const int* __restrict__ isamp, float* __restrict__ out, int KS) {
  __shared__ float kT[8][256];                     // 8 KB, [k][c]
  __shared__ __align__(16) _Float16 vT[64][256];   // 32 KB, [d][c] swizzled
  __shared__ __align__(16) _Float16 Pm[32][256];   // 16 KB, [u][c] swizzled
  __shared__ float qsel[NS][8];
  __shared__ float MvC[256];
  __shared__ float csum4[4][64];
  __shared__ int idxl[NS];
  __shared__ int flagl[256];

  const int bh = blockIdx.x;
  const int b = bh >> 4, h = bh & 15;
  const int tid = threadIdx.x;
  const int w = tid >> 6, lane = tid & 63;
  const float* qpl = P;                        // q planes [0..KS)
  const float* kpl = P + (size_t)KS * PLANE;   // k planes [0..KS)
  float* obase = out + (size_t)bh * 16384;

  // ---- phase 0: kT (reduced+biased, transposed), vT f16, qq regs, flags ----
  float qq[8];
  {
    float ks8[8];
    size_t rowo = (size_t)bh * CKN + tid * 8;
#pragma unroll
    for (int k = 0; k < 8; ++k) ks8[k] = 0.0f;
    for (int p = 0; p < KS; ++p) {
      float4 a0 = *(const float4*)(kpl + p * PLANE + rowo);
      float4 a1 = *(const float4*)(kpl + p * PLANE + rowo + 4);
      ks8[0] += a0.x; ks8[1] += a0.y; ks8[2] += a0.z; ks8[3] += a0.w;
      ks8[4] += a1.x; ks8[5] += a1.y; ks8[6] += a1.z; ks8[7] += a1.w;
    }
    float4 b0 = *(const float4*)(bk + tid * 8);
    float4 b1 = *(const float4*)(bk + tid * 8 + 4);
    const float* bp = &b0.x;
    kT[0][tid] = ks8[0] * SCLQ + b0.x; kT[1][tid] = ks8[1] * SCLQ + b0.y;
    kT[2][tid] = ks8[2] * SCLQ + b0.z; kT[3][tid] = ks8[3] * SCLQ + b0.w;
    kT[4][tid] = ks8[4] * SCLQ + b1.x; kT[5][tid] = ks8[5] * SCLQ + b1.y;
    kT[6][tid] = ks8[6] * SCLQ + b1.z; kT[7][tid] = ks8[7] * SCLQ + b1.w;
    (void)bp;
    // qq: this thread's own q row
#pragma unroll
    for (int k = 0; k < 8; ++k) qq[k] = 0.0f;
    for (int p = 0; p < KS; ++p) {
      float4 a0 = *(const float4*)(qpl + p * PLANE + rowo);
      float4 a1 = *(const float4*)(qpl + p * PLANE + rowo + 4);
      qq[0] += a0.x; qq[1] += a0.y; qq[2] += a0.z; qq[3] += a0.w;
      qq[4] += a1.x; qq[5] += a1.y; qq[6] += a1.z; qq[7] += a1.w;
    }
    float4 c0 = *(const float4*)(bq + tid * 8);
    float4 c1 = *(const float4*)(bq + tid * 8 + 4);
    qq[0] = qq[0] * SCLQ + c0.x; qq[1] = qq[1] * SCLQ + c0.y;
    qq[2] = qq[2] * SCLQ + c0.z; qq[3] = qq[3] * SCLQ + c0.w;
    qq[4] = qq[4] * SCLQ + c1.x; qq[5] = qq[5] * SCLQ + c1.y;
    qq[6] = qq[6] * SCLQ + c1.z; qq[7] = qq[7] * SCLQ + c1.w;
    // vT: values[b,c,h,d] -> vT[d][c] f16 (chunk-swizzled)
    const float* vbase = values + (size_t)b * 262144 + h * 64;
#pragma unroll
    for (int rep = 0; rep < 16; ++rep) {
      int i = rep * 256 + tid;
      int c = i >> 4, dg = i & 15;
      float4 v = *(const float4*)(vbase + (size_t)c * 1024 + dg * 4);
      const float* vp = &v.x;
#pragma unroll
      for (int j = 0; j < 4; ++j) {
        int d = dg * 4 + j;
        vT[d][(((c >> 3) ^ (d & 7)) << 3) | (c & 7)] = (_Float16)vp[j];
      }
    }
    flagl[tid] = 0;
    if (tid < 64) {  // zero Pm pad rows 30,31
#pragma unroll
      for (int rr = 30; rr < 32; ++rr) {
        int ci = tid >> 1;
        *(h4*)&Pm[rr][((ci ^ (rr & 7)) << 3) | ((tid * 4) & 7)] =
            (h4){(_Float16)0, (_Float16)0, (_Float16)0, (_Float16)0};
      }
    }
  }
  __syncthreads();

  // ---- phase 1: M[c] = max_s QKs - sum_s QKs / 256 ----
  {
    float mx = -INFINITY, sm = 0.0f;
    const int* ip = isamp + tid * NS;
#pragma unroll 6
    for (int s = 0; s < NS; ++s) {
      int j = ip[s];
      float dot = 0.0f;
#pragma unroll
      for (int k = 0; k < NK; ++k) dot += qq[k] * kT[k][j];
      mx = fmaxf(mx, dot);
      sm += dot;
    }
    MvC[tid] = mx - sm * (1.0f / 256.0f);
  }
  __syncthreads();

  // ---- phase 2: top-30, single wave, shfl argmax (tie -> lower index) ----
  if (tid < 64) {
    float m0 = MvC[tid], m1 = MvC[tid + 64], m2 = MvC[tid + 128], m3 = MvC[tid + 192];
    for (int u = 0; u < NS; ++u) {
      float bv = m0; int bi = tid;
      if (m1 > bv) { bv = m1; bi = tid + 64; }
      if (m2 > bv) { bv = m2; bi = tid + 128; }
      if (m3 > bv) { bv = m3; bi = tid + 192; }
#pragma unroll
      for (int off = 32; off > 0; off >>= 1) {
        float ov = __shfl_xor(bv, off);
        int oi = __shfl_xor(bi, off);
        if (ov > bv || (ov == bv && oi < bi)) { bv = ov; bi = oi; }
      }
      if (tid == 0) { idxl[u] = bi; flagl[bi] = u + 1; }
      if (tid == (bi & 63)) {
        switch (bi >> 6) {
          case 0: m0 = -INFINITY; break;
          case 1: m1 = -INFINITY; break;
          case 2: m2 = -INFINITY; break;
          default: m3 = -INFINITY; break;
        }
      }
    }
  }
  __syncthreads();

  // ---- phase 3: gather selected q rows (reduced+biased) ----
  if (tid < NS * 8) {
    int u = tid >> 3, k = tid & 7;
    size_t off = (size_t)bh * CKN + idxl[u] * 8 + k;
    float s = 0.0f;
    for (int p = 0; p < KS; ++p) s += qpl[p * PLANE + off];
    qsel[u][k] = s * SCLQ + bq[idxl[u] * 8 + k];
  }
  __syncthreads();

  // ---- phase 4: per-wave u: scores -> softmax -> Pm (f16) ----
  for (int ui = w; ui < NS; ui += 4) {
    const int qi = idxl[ui];
    float qv[8];
#pragma unroll
    for (int k = 0; k < 8; ++k) qv[k] = qsel[ui][k];   // LDS broadcast
    float sj[4];
#pragma unroll
    for (int j = 0; j < 4; ++j) {
      int c = j * 64 + lane;
      float s = 0.0f;
#pragma unroll
      for (int k = 0; k < NK; ++k) s += qv[k] * kT[k][c];
      sj[j] = (c > qi) ? -INFINITY : s * 0.125f;       // SCALE=1/8, causal
    }
    float m = fmaxf(fmaxf(sj[0], sj[1]), fmaxf(sj[2], sj[3]));
#pragma unroll
    for (int off = 32; off > 0; off >>= 1) m = fmaxf(m, __shfl_xor(m, off));
    float pj[4], ts = 0.0f;
#pragma unroll
    for (int j = 0; j < 4; ++j) { pj[j] = __expf(sj[j] - m); ts += pj[j]; }
#pragma unroll
    for (int off = 32; off > 0; off >>= 1) ts += __shfl_xor(ts, off);
    float rinv = 1.0f / ts;
#pragma unroll
    for (int j = 0; j < 4; ++j) {
      int c = j * 64 + lane;
      Pm[ui][(((c >> 3) ^ (ui & 7)) << 3) | (c & 7)] = (_Float16)(pj[j] * rinv);
    }
  }
  __syncthreads();

  // ---- phase 5: upd = Pm(32x256) @ vT(256x64) via MFMA; wave w owns d-quarter
  {
    const int lr = lane & 15, lk = lane >> 4;
    f4v pacc[2];
    pacc[0] = (f4v){0.f, 0.f, 0.f, 0.f};
    pacc[1] = (f4v){0.f, 0.f, 0.f, 0.f};
#pragma unroll
    for (int kc = 0; kc < 8; ++kc) {
      int cidx = kc * 4 + lk;
      h8 Bv = *(const h8*)&vT[w * 16 + lr][((cidx ^ (lr & 7)) << 3)];
#pragma unroll
      for (int mf = 0; mf < 2; ++mf) {
        h8 Ap = *(const h8*)&Pm[mf * 16 + lr][((cidx ^ (lr & 7)) << 3)];
        pacc[mf] = __builtin_amdgcn_mfma_f32_16x16x32_f16(Ap, Bv, pacc[mf], 0, 0, 0);
      }
    }
#pragma unroll
    for (int mf = 0; mf < 2; ++mf)
#pragma unroll
      for (int j = 0; j < 4; ++j) {
        int u = mf * 16 + lk * 4 + j;
        if (u < NS) obase[(size_t)idxl[u] * 64 + w * 16 + lr] = pacc[mf][j];
      }
  }

  // ---- phase 6: cumsum(v) along l (f16 source), skip flagged rows ----
  {
    float cs = 0.0f;
#pragma unroll 8
    for (int i = 0; i < 64; ++i) {
      int c = w * 64 + i;
      cs += (float)vT[lane][(((c >> 3) ^ (lane & 7)) << 3) | (c & 7)];
    }
    csum4[w][lane] = cs;
    __syncthreads();
    float run = 0.0f;
    for (int j2 = 0; j2 < w; ++j2) run += csum4[j2][lane];
    for (int i = 0; i < 64; ++i) {
      int l = w * 64 + i;
      run += (float)vT[lane][(((l >> 3) ^ (lane & 7)) << 3) | (l & 7)];
      if (!flagl[l]) obase[(size_t)l * 64 + lane] = run;
    }
  }
}

extern "C" void kernel_launch(void* const* d_in, const int* in_sizes, int n_in,
                              void* d_out, int out_size, void* d_ws, size_t ws_size,
                              hipStream_t stream) {
  (void)in_sizes; (void)n_in; (void)out_size;
  const float* queries = (const float*)d_in[0];
  const float* keys = (const float*)d_in[1];
  const float* values = (const float*)d_in[2];
  const float* Wq_w = (const float*)d_in[3];
  const float* Wq_b = (const float*)d_in[4];
  const float* Wk_w = (const float*)d_in[5];
  const float* Wk_b = (const float*)d_in[6];
  // d_in[7], d_in[8] (Wv_w, Wv_b): dead in reference. d_in[10] attn_mask: unused.
  const int* index_sample = (const int*)d_in[9];
  float* out = (float*)d_out;

  float* P = (float*)d_ws;   // 2*KS partial planes [z][ks][1024][2048] f32

  // KS=4 needs 67.1 MB ws; fall back to KS=2 (33.5 MB, proven) if short.
  const int KS = (ws_size >= (size_t)8 * PLANE * 4) ? 4 : 2;
  const int KL = ICHN / KS;
  const int nsteps = KL / 32;

  dim3 gridG(32, KS, 2);
  gemm_split3<<<gridG, 512, 0, stream>>>(queries, keys, Wq_w, Wk_w, P, KS, KL, nsteps);
  attn_tail<<<dim3(MROWS), 256, 0, stream>>>(P, Wq_b, Wk_b, values, index_sample, out, KS);
}